// Round 9
// baseline (136.627 us; speedup 1.0000x reference)
//
#include <hip/hip_runtime.h>

#define ALPHA 0.2f

typedef __attribute__((ext_vector_type(8))) short short8;
typedef __attribute__((ext_vector_type(8))) unsigned short ushort8;
typedef __attribute__((ext_vector_type(4))) float f32x4;

__device__ __forceinline__ float bf2f(unsigned short u) {
    return __uint_as_float(((unsigned int)u) << 16);
}
__device__ __forceinline__ unsigned short f2bf(float f) {
    unsigned int x = __float_as_uint(f);
    unsigned int r = (x + 0x7fffu + ((x >> 16) & 1u)) >> 16;   // RNE
    return (unsigned short)r;
}
// order-preserving float<->uint encode for atomicMax
__device__ __forceinline__ unsigned int encf(float f) {
    int i = __float_as_int(f);
    return (unsigned int)(i ^ ((i >> 31) | 0x80000000));
}
__device__ __forceinline__ float decf(unsigned int u) {
    int i = (int)((u & 0x80000000u) ? (u ^ 0x80000000u) : ~u);
    return __int_as_float(i);
}

// Per-wave fp32-vs-bf16 detection on x's low u16 bf16-exponent plausibility.
__device__ __forceinline__ int detect_is32(const unsigned int* xw) {
    int lane = threadIdx.x & 63;
    unsigned int u = xw[lane];
    unsigned int e = (u >> 7) & 0xffu;
    unsigned long long b = __ballot(e >= 0x58u && e <= 0x90u);
    return (__popcll(b) < 40) ? 1 : 0;
}

// ---------------------------------------------------------------------------
// Kernel 1: split fp32 -> bf16 hi/lo planes; publishes flags[0]; zeroes gmax.
// x planes [N][C]; W planes TRANSPOSED to [H][F][C].
// ---------------------------------------------------------------------------
__global__ __launch_bounds__(256) void split_bf16(const void* __restrict__ x_raw,
                                                  const void* __restrict__ W_raw,
                                                  unsigned short* __restrict__ x_hi,
                                                  unsigned short* __restrict__ x_lo,
                                                  unsigned short* __restrict__ wt_hi,
                                                  unsigned short* __restrict__ wt_lo,
                                                  int* __restrict__ flags) {
    int bid = blockIdx.x, tid = threadIdx.x;
    int is32 = detect_is32((const unsigned int*)x_raw);
    if (bid == 0 && tid == 0) flags[0] = is32;
    if (bid == 0 && tid >= 8 && tid < 16) flags[tid] = 0;   // gmax enc init

    if (bid < 1024) {
        size_t base = ((size_t)bid * 256 + tid) * 8;
        ushort8 h8, l8;
        if (is32) {
            const float* xf = (const float*)x_raw;
            float4 v0 = *(const float4*)(xf + base);
            float4 v1 = *(const float4*)(xf + base + 4);
            float v[8] = {v0.x, v0.y, v0.z, v0.w, v1.x, v1.y, v1.z, v1.w};
#pragma unroll
            for (int j = 0; j < 8; j++) {
                unsigned short hi = f2bf(v[j]);
                h8[j] = hi;
                l8[j] = f2bf(v[j] - bf2f(hi));
            }
        } else {
            const ushort8* xb = (const ushort8*)x_raw;
            h8 = xb[base / 8];
            l8 = (ushort8)0;
        }
        *(ushort8*)(x_hi + base) = h8;
        *(ushort8*)(x_lo + base) = l8;
    } else {
        size_t u = ((size_t)(bid - 1024) * 256 + tid) * 8;
#pragma unroll
        for (int j = 0; j < 8; j++) {
            size_t e = u + j;
            int head = (int)(e >> 15);
            int c = (int)((e >> 6) & 511);
            int f = (int)(e & 63);
            unsigned short hi, lo;
            if (is32) {
                float v = ((const float*)W_raw)[e];
                hi = f2bf(v);
                lo = f2bf(v - bf2f(hi));
            } else {
                hi = ((const unsigned short*)W_raw)[e];
                lo = 0;
            }
            size_t o = (size_t)head * 32768 + (size_t)f * 512 + c;
            wt_hi[o] = hi;
            wt_lo[o] = lo;
        }
    }
}

// ---------------------------------------------------------------------------
// Kernel 2: adjacency bitmask; self-detects int64 vs int32 edge_index.
// ---------------------------------------------------------------------------
__global__ __launch_bounds__(256) void build_adj(const int* __restrict__ ei, int E, int N,
                                                 unsigned long long* __restrict__ adj) {
    int lane = threadIdx.x & 63;
    unsigned long long nz = __ballot(ei[2 * lane + 1] != 0);
    int is64 = (nz == 0ull) ? 1 : 0;

    int t = blockIdx.x * blockDim.x + threadIdx.x;
    int words = N >> 6;
    if (t < E) {
        int r = is64 ? ei[2 * t]       : ei[t];
        int c = is64 ? ei[2 * (E + t)] : ei[E + t];
        atomicOr(&adj[(size_t)r * words + (c >> 6)], 1ull << (c & 63));
    } else if (t < E + N) {
        int i = t - E;
        atomicOr(&adj[(size_t)i * words + (i >> 6)], 1ull << (i & 63));
    }
}

// ---------------------------------------------------------------------------
// Kernel 3: MFMA GEMM (bf16x3), per-wave K-split, BARRIER-FREE K-loop.
// Block 64x64 (by=head). Wave w owns K-chunks w*12..w*12+11 (k=32 each,
// K'=1536 over planes {xh*wth, xl*wth, xh*wtl}), stages its own chunks into
// a private double-buffered LDS region, computes the full 64x64 tile as a
// 4x4 outer product of 16x16x32 MFMAs. Cross-wave fp32 reduce in epilogue.
// ---------------------------------------------------------------------------
#define LR 36
__global__ __launch_bounds__(256, 2) void gemm_mfma(const unsigned short* __restrict__ xh,
                                                    const unsigned short* __restrict__ xl,
                                                    const unsigned short* __restrict__ wth,
                                                    const unsigned short* __restrict__ wtl,
                                                    const void* __restrict__ a_raw,
                                                    unsigned short* __restrict__ h2b,
                                                    float* __restrict__ s_src2,
                                                    float* __restrict__ s_dst2,
                                                    int* __restrict__ flags) {
    // [wave][buf][A=0/B=1][64*LR]  = 73,728 B
    __shared__ unsigned short sbuf[4][2][2][64 * LR];

    int head = blockIdx.y;
    int row0 = blockIdx.x * 64;
    int tid = threadIdx.x;
    int w = tid >> 6, lane = tid & 63;
    int m = lane & 15, quad = lane >> 4;
    int srow = lane >> 2, skc = lane & 3;
    size_t wbase = (size_t)head * 32768;

    const unsigned short* Ap[3] = {xh, xl, xh};
    const unsigned short* Bp[3] = {wth, wth, wtl};

    f32x4 acc[4][4];
#pragma unroll
    for (int a = 0; a < 4; a++)
#pragma unroll
        for (int b = 0; b < 4; b++) acc[a][b] = f32x4{0.f, 0.f, 0.f, 0.f};

#define LOADC(RA, RB, c)                                                        \
    {                                                                           \
        const unsigned short* pA = Ap[(c) >> 4];                                \
        const unsigned short* pB = Bp[(c) >> 4];                                \
        size_t ko = (size_t)((c) & 15) * 32;                                    \
        _Pragma("unroll")                                                       \
        for (int p = 0; p < 4; p++) {                                           \
            RA[p] = *(const ushort8*)(pA + (size_t)(row0 + p * 16 + srow) * 512 + ko + skc * 8); \
            RB[p] = *(const ushort8*)(pB + wbase + (size_t)(p * 16 + srow) * 512 + ko + skc * 8); \
        }                                                                       \
    }

#define WRITEC(buf, RA, RB)                                                     \
    {                                                                           \
        _Pragma("unroll")                                                       \
        for (int p = 0; p < 4; p++) {                                           \
            *(ushort8*)&sbuf[w][buf][0][(p * 16 + srow) * LR + skc * 8] = RA[p]; \
            *(ushort8*)&sbuf[w][buf][1][(p * 16 + srow) * LR + skc * 8] = RB[p]; \
        }                                                                       \
    }

#define COMPUTEC(buf)                                                           \
    {                                                                           \
        short8 af[4], bfr[4];                                                   \
        _Pragma("unroll")                                                       \
        for (int t = 0; t < 4; t++) {                                           \
            af[t]  = *(const short8*)&sbuf[w][buf][0][(t * 16 + m) * LR + quad * 8]; \
            bfr[t] = *(const short8*)&sbuf[w][buf][1][(t * 16 + m) * LR + quad * 8]; \
        }                                                                       \
        _Pragma("unroll")                                                       \
        for (int mt = 0; mt < 4; mt++)                                          \
            _Pragma("unroll")                                                   \
            for (int nt = 0; nt < 4; nt++)                                      \
                acc[mt][nt] = __builtin_amdgcn_mfma_f32_16x16x32_bf16(af[mt], bfr[nt], acc[mt][nt], 0, 0, 0); \
    }

    int c0 = w * 12;
    ushort8 eA[4], eB[4], oA[4], oB[4];
    LOADC(eA, eB, c0)
    LOADC(oA, oB, c0 + 1)
    WRITEC(0, eA, eB)

    for (int ci = 0; ci < 12; ci += 2) {
        if (ci + 2 < 12) LOADC(eA, eB, c0 + ci + 2)
        COMPUTEC(0)
        WRITEC(1, oA, oB)
        if (ci + 3 < 12) LOADC(oA, oB, c0 + ci + 3)
        COMPUTEC(1)
        if (ci + 2 < 12) WRITEC(0, eA, eB)
    }

    // ---- cross-wave reduction epilogue ----
    float* sp = (float*)&sbuf[0][0][0][0];       // 64 KB scratch (fits in 73.7 KB)
    __syncthreads();
#pragma unroll
    for (int mt = 0; mt < 4; mt++)
#pragma unroll
        for (int nt = 0; nt < 4; nt++)
#pragma unroll
            for (int reg = 0; reg < 4; reg++) {
                int row = mt * 16 + quad * 4 + reg;
                sp[w * 4096 + row * 64 + nt * 16 + m] = acc[mt][nt][reg];
            }
    __syncthreads();

    int r = tid >> 2, cc = tid & 3;              // row 0..63, 16-col chunk 0..3
    float c16[16];
#pragma unroll
    for (int i = 0; i < 16; i++) c16[i] = 0.f;
#pragma unroll
    for (int g = 0; g < 4; g++) {
        const float* q = sp + g * 4096 + r * 64 + cc * 16;
#pragma unroll
        for (int v = 0; v < 4; v++) {
            float4 f = *(const float4*)(q + v * 4);
            c16[v * 4 + 0] += f.x; c16[v * 4 + 1] += f.y;
            c16[v * 4 + 2] += f.z; c16[v * 4 + 3] += f.w;
        }
    }

    // h2b write (bf16), 32B per thread
    ushort8 pk0, pk1;
#pragma unroll
    for (int i = 0; i < 8; i++) { pk0[i] = f2bf(c16[i]); pk1[i] = f2bf(c16[8 + i]); }
    unsigned short* hb = h2b + (size_t)(row0 + r) * 512 + head * 64 + cc * 16;
    *(ushort8*)hb = pk0;
    *(ushort8*)(hb + 8) = pk1;

    // s_src/s_dst from exact fp32 sums
    float as[16], ad[16];
    if (flags[0]) {
        const float* af = (const float*)a_raw + head * 128 + cc * 16;
#pragma unroll
        for (int i = 0; i < 16; i++) { as[i] = af[i]; ad[i] = af[64 + i]; }
    } else {
        const unsigned short* ab = (const unsigned short*)a_raw + head * 128 + cc * 16;
#pragma unroll
        for (int i = 0; i < 16; i++) { as[i] = bf2f(ab[i]); ad[i] = bf2f(ab[64 + i]); }
    }
    float s1 = 0.f, s2 = 0.f;
#pragma unroll
    for (int i = 0; i < 16; i++) { s1 += c16[i] * as[i]; s2 += c16[i] * ad[i]; }
    s1 += __shfl_xor(s1, 1); s1 += __shfl_xor(s1, 2);
    s2 += __shfl_xor(s2, 1); s2 += __shfl_xor(s2, 2);
    if ((tid & 3) == 0) {
        s_src2[(size_t)(row0 + r) * 8 + head] = s1;
        s_dst2[(size_t)(row0 + r) * 8 + head] = s2;
    }
    // global per-head max of s_dst (for attn softmax bound)
    float gm = s2;
#pragma unroll
    for (int d = 4; d < 64; d <<= 1) gm = fmaxf(gm, __shfl_xor(gm, d));
    if (lane == 0) atomicMax((unsigned int*)&flags[8 + head], encf(gm));
}

// ---------------------------------------------------------------------------
// Kernel 4: attention + aggregation + row softmax. Block per node i.
// Per-row softmax bound comes from the GLOBAL per-head s_dst max (no
// neighbor max pass). Weight pass: 8 exps/neighbor into LDS; acc pass:
// coalesced bf16 h2b gathers.
// ---------------------------------------------------------------------------
__global__ __launch_bounds__(256) void attn_out(const unsigned short* __restrict__ h2b,
                                                const float* __restrict__ s_src2,
                                                const float* __restrict__ s_dst2,
                                                const unsigned long long* __restrict__ adj,
                                                void* __restrict__ out_raw,
                                                const int* __restrict__ flags) {
    __shared__ unsigned short nbrs[4096];
    __shared__ float w_lds[256 * 8];
    __shared__ float sss[8], smax[8], sden[8];
    __shared__ float sredw[4][8];
    __shared__ float sr[8];
    __shared__ int s_cnt;

    int i = blockIdx.x;
    int tid = threadIdx.x;
    int lane = tid & 63, wid = tid >> 6;

    if (tid < 64) {
        unsigned long long word = adj[(size_t)i * 64 + tid];
        int cnt = __popcll(word);
        int incl = cnt;
#pragma unroll
        for (int d = 1; d < 64; d <<= 1) {
            int v = __shfl_up(incl, d);
            if (tid >= d) incl += v;
        }
        int off = incl - cnt;
        unsigned long long w = word;
        int base = tid * 64;
        while (w) {
            int b = __ffsll((unsigned long long)w) - 1;
            nbrs[off++] = (unsigned short)(base + b);
            w &= w - 1;
        }
        if (tid == 63) s_cnt = incl;
    }
    if (tid >= 64 && tid < 72) {
        int h = tid - 64;
        float ss = s_src2[(size_t)i * 8 + h];
        sss[h] = ss;
        float pre = ss + decf((unsigned int)flags[8 + h]);
        smax[h] = pre > 0.f ? pre : ALPHA * pre;
    }
    __syncthreads();
    int cnt = s_cnt;

    int hw = tid & 7;
    int hh = tid >> 5;
    float ssrc_w = sss[hw], maxe_w = smax[hw];
    float den = 0.f, ax = 0.f, ay = 0.f;
    for (int c0 = 0; c0 < cnt; c0 += 256) {
        int csz = min(256, cnt - c0);
        __syncthreads();
        for (int t = tid; t < csz * 8; t += 256) {
            int j = nbrs[c0 + (t >> 3)];
            float e = ssrc_w + s_dst2[(size_t)j * 8 + hw];
            e = e > 0.f ? e : ALPHA * e;
            float w = __expf(e - maxe_w);
            w_lds[t] = w;
            den += w;
        }
        __syncthreads();
#pragma unroll 2
        for (int jj = 0; jj < csz; jj++) {
            int j = nbrs[c0 + jj];
            unsigned int u = *(const unsigned int*)(h2b + (size_t)j * 512 + tid * 2);
            float w = w_lds[jj * 8 + hh];
            ax += w * bf2f((unsigned short)(u & 0xffffu));
            ay += w * bf2f((unsigned short)(u >> 16));
        }
    }

    den += __shfl_down(den, 32);
    den += __shfl_down(den, 16);
    den += __shfl_down(den, 8);
    if (lane < 8) sredw[wid][lane] = den;
    __syncthreads();
    if (tid < 8) sden[tid] = sredw[0][tid] + sredw[1][tid] + sredw[2][tid] + sredw[3][tid];
    __syncthreads();
    float dtot = sden[hh];
    float o0 = ax / dtot, o1 = ay / dtot;

    float m2 = fmaxf(o0, o1);
#pragma unroll
    for (int d = 32; d; d >>= 1) m2 = fmaxf(m2, __shfl_down(m2, d));
    if (lane == 0) sr[wid] = m2;
    __syncthreads();
    float m = fmaxf(fmaxf(sr[0], sr[1]), fmaxf(sr[2], sr[3]));
    float e0 = __expf(o0 - m), e1 = __expf(o1 - m);
    float s = e0 + e1;
#pragma unroll
    for (int d = 32; d; d >>= 1) s += __shfl_down(s, d);
    __syncthreads();
    if (lane == 0) sr[wid + 4] = s;
    __syncthreads();
    s = sr[4] + sr[5] + sr[6] + sr[7];

    if (flags[0]) {
        float2* out = (float2*)out_raw;
        out[(size_t)i * 256 + tid] = make_float2(e0 / s, e1 / s);
    } else {
        unsigned int* out = (unsigned int*)out_raw;
        out[(size_t)i * 256 + tid] = (unsigned int)f2bf(e0 / s) | ((unsigned int)f2bf(e1 / s) << 16);
    }
}

// ---------------------------------------------------------------------------
extern "C" void kernel_launch(void* const* d_in, const int* in_sizes, int n_in,
                              void* d_out, int out_size, void* d_ws, size_t ws_size,
                              hipStream_t stream) {
    const int N = 4096, H = 8;
    const int E = in_sizes[1] / 2;

    const void* x = d_in[0];
    const int*  ei = (const int*)d_in[1];
    const void* W = d_in[2];
    const void* a = d_in[3];

    char* ws = (char*)d_ws;
    unsigned short* h2b = (unsigned short*)ws;                           // 4 MB
    float* s_src2 = (float*)(ws + (size_t)4 * 1024 * 1024);              // 128 KB
    float* s_dst2 = s_src2 + (size_t)N * H;                              // 128 KB
    unsigned long long* adj = (unsigned long long*)(ws + (size_t)5 * 1024 * 1024); // 2 MB
    int* flags = (int*)(ws + (size_t)7 * 1024 * 1024 + 512 * 1024);      // flags[0..7], gmax enc [8..15]
    unsigned short* x_hi  = (unsigned short*)(ws + (size_t)8 * 1024 * 1024);       // 4 MB
    unsigned short* x_lo  = (unsigned short*)(ws + (size_t)12 * 1024 * 1024);      // 4 MB
    unsigned short* wt_hi = (unsigned short*)(ws + (size_t)16 * 1024 * 1024);      // 512 KB
    unsigned short* wt_lo = (unsigned short*)(ws + (size_t)16 * 1024 * 1024 + 512 * 1024);

    hipMemsetAsync(adj, 0, (size_t)N * (N / 8), stream);

    split_bf16<<<1152, 256, 0, stream>>>(x, W, x_hi, x_lo, wt_hi, wt_lo, flags);
    build_adj<<<(E + N + 255) / 256, 256, 0, stream>>>(ei, E, N, adj);
    gemm_mfma<<<dim3(N / 64, H), 256, 0, stream>>>(x_hi, x_lo, wt_hi, wt_lo, a,
                                                   h2b, s_src2, s_dst2, flags);
    attn_out<<<N, 256, 0, stream>>>(h2b, s_src2, s_dst2, adj, d_out, flags);
}

// Round 10
// 133.070 us; speedup vs baseline: 1.0267x; 1.0267x over previous
//
#include <hip/hip_runtime.h>

#define ALPHA 0.2f

typedef __attribute__((ext_vector_type(8))) short short8;
typedef __attribute__((ext_vector_type(8))) unsigned short ushort8;
typedef __attribute__((ext_vector_type(4))) float f32x4;

__device__ __forceinline__ float bf2f(unsigned short u) {
    return __uint_as_float(((unsigned int)u) << 16);
}
__device__ __forceinline__ unsigned short f2bf(float f) {
    unsigned int x = __float_as_uint(f);
    unsigned int r = (x + 0x7fffu + ((x >> 16) & 1u)) >> 16;   // RNE
    return (unsigned short)r;
}
// order-preserving float<->uint encode for atomicMax
__device__ __forceinline__ unsigned int encf(float f) {
    int i = __float_as_int(f);
    return (unsigned int)(i ^ ((i >> 31) | 0x80000000));
}
__device__ __forceinline__ float decf(unsigned int u) {
    int i = (int)((u & 0x80000000u) ? (u ^ 0x80000000u) : ~u);
    return __int_as_float(i);
}

// Per-wave fp32-vs-bf16 detection on x's low u16 bf16-exponent plausibility.
__device__ __forceinline__ int detect_is32(const unsigned int* xw) {
    int lane = threadIdx.x & 63;
    unsigned int u = xw[lane];
    unsigned int e = (u >> 7) & 0xffu;
    unsigned long long b = __ballot(e >= 0x58u && e <= 0x90u);
    return (__popcll(b) < 40) ? 1 : 0;
}

// ---------------------------------------------------------------------------
// Kernel 1: split fp32 -> bf16 hi/lo planes; publishes flags[0]; zeroes gmax.
// x planes [N][C]; W planes TRANSPOSED to [H][F][C].
// ---------------------------------------------------------------------------
__global__ __launch_bounds__(256) void split_bf16(const void* __restrict__ x_raw,
                                                  const void* __restrict__ W_raw,
                                                  unsigned short* __restrict__ x_hi,
                                                  unsigned short* __restrict__ x_lo,
                                                  unsigned short* __restrict__ wt_hi,
                                                  unsigned short* __restrict__ wt_lo,
                                                  int* __restrict__ flags) {
    int bid = blockIdx.x, tid = threadIdx.x;
    int is32 = detect_is32((const unsigned int*)x_raw);
    if (bid == 0 && tid == 0) flags[0] = is32;
    if (bid == 0 && tid >= 8 && tid < 16) flags[tid] = 0;   // gmax enc init

    if (bid < 1024) {
        size_t base = ((size_t)bid * 256 + tid) * 8;
        ushort8 h8, l8;
        if (is32) {
            const float* xf = (const float*)x_raw;
            float4 v0 = *(const float4*)(xf + base);
            float4 v1 = *(const float4*)(xf + base + 4);
            float v[8] = {v0.x, v0.y, v0.z, v0.w, v1.x, v1.y, v1.z, v1.w};
#pragma unroll
            for (int j = 0; j < 8; j++) {
                unsigned short hi = f2bf(v[j]);
                h8[j] = hi;
                l8[j] = f2bf(v[j] - bf2f(hi));
            }
        } else {
            const ushort8* xb = (const ushort8*)x_raw;
            h8 = xb[base / 8];
            l8 = (ushort8)0;
        }
        *(ushort8*)(x_hi + base) = h8;
        *(ushort8*)(x_lo + base) = l8;
    } else {
        size_t u = ((size_t)(bid - 1024) * 256 + tid) * 8;
#pragma unroll
        for (int j = 0; j < 8; j++) {
            size_t e = u + j;
            int head = (int)(e >> 15);
            int c = (int)((e >> 6) & 511);
            int f = (int)(e & 63);
            unsigned short hi, lo;
            if (is32) {
                float v = ((const float*)W_raw)[e];
                hi = f2bf(v);
                lo = f2bf(v - bf2f(hi));
            } else {
                hi = ((const unsigned short*)W_raw)[e];
                lo = 0;
            }
            size_t o = (size_t)head * 32768 + (size_t)f * 512 + c;
            wt_hi[o] = hi;
            wt_lo[o] = lo;
        }
    }
}

// ---------------------------------------------------------------------------
// Kernel 2: adjacency bitmask; self-detects int64 vs int32 edge_index.
// ---------------------------------------------------------------------------
__global__ __launch_bounds__(256) void build_adj(const int* __restrict__ ei, int E, int N,
                                                 unsigned long long* __restrict__ adj) {
    int lane = threadIdx.x & 63;
    unsigned long long nz = __ballot(ei[2 * lane + 1] != 0);
    int is64 = (nz == 0ull) ? 1 : 0;

    int t = blockIdx.x * blockDim.x + threadIdx.x;
    int words = N >> 6;
    if (t < E) {
        int r = is64 ? ei[2 * t]       : ei[t];
        int c = is64 ? ei[2 * (E + t)] : ei[E + t];
        atomicOr(&adj[(size_t)r * words + (c >> 6)], 1ull << (c & 63));
    } else if (t < E + N) {
        int i = t - E;
        atomicOr(&adj[(size_t)i * words + (i >> 6)], 1ull << (i & 63));
    }
}

// ---------------------------------------------------------------------------
// Kernel 3: MFMA GEMM (bf16x3), BK=64, shared LDS double-buffer (r8 winner:
// one barrier per K-iter, 24 iters, depth-2 global prefetch).
// Block 64x64 (one head), 4 waves x 4 tiles of 16x16x32.
// Epilogue additionally publishes global per-head max(s_dst) via atomicMax.
// ---------------------------------------------------------------------------
#define LROW 72
__global__ __launch_bounds__(256) void gemm_mfma(const unsigned short* __restrict__ xh,
                                                 const unsigned short* __restrict__ xl,
                                                 const unsigned short* __restrict__ wth,
                                                 const unsigned short* __restrict__ wtl,
                                                 const void* __restrict__ a_raw,
                                                 unsigned short* __restrict__ h2b,
                                                 float* __restrict__ s_src2,
                                                 float* __restrict__ s_dst2,
                                                 int* __restrict__ flags) {
    __shared__ unsigned short sA[2][64 * LROW];
    __shared__ unsigned short sB[2][64 * LROW];

    int head = blockIdx.y;
    int row0 = blockIdx.x * 64;
    int tid = threadIdx.x;
    int w = tid >> 6, lane = tid & 63;
    int m = lane & 15, quad = lane >> 4;
    int srow = tid >> 2, sc = tid & 3;

    const unsigned short* Ap[3] = {xh, xl, xh};
    const unsigned short* Bp[3] = {wth, wth, wtl};
    size_t baseA = (size_t)(row0 + srow) * 512 + sc * 8;
    size_t baseB = (size_t)head * 32768 + (size_t)srow * 512 + sc * 8;

    int ldsw  = srow * LROW + sc * 8;
    int ldsAr = (w * 16 + m) * LROW + quad * 8;

    f32x4 acc[4] = {f32x4{0.f, 0.f, 0.f, 0.f}, f32x4{0.f, 0.f, 0.f, 0.f},
                    f32x4{0.f, 0.f, 0.f, 0.f}, f32x4{0.f, 0.f, 0.f, 0.f}};

    // iter c (0..23): plane = c>>3, k-offset = (c&7)*64; chunks at +0 and +32.
#define LOADSET(Aa, Ab, Ba, Bb, c)                                         \
    {                                                                      \
        const unsigned short* pA = Ap[(c) >> 3];                           \
        const unsigned short* pB = Bp[(c) >> 3];                           \
        size_t ko = (size_t)((c) & 7) * 64;                                \
        Aa = *(const ushort8*)(pA + baseA + ko);                           \
        Ab = *(const ushort8*)(pA + baseA + ko + 32);                      \
        Ba = *(const ushort8*)(pB + baseB + ko);                           \
        Bb = *(const ushort8*)(pB + baseB + ko + 32);                      \
    }

#define WRITESET(buf, Aa, Ab, Ba, Bb)                                      \
    {                                                                      \
        *(ushort8*)&sA[buf][ldsw]      = Aa;                               \
        *(ushort8*)&sA[buf][ldsw + 32] = Ab;                               \
        *(ushort8*)&sB[buf][ldsw]      = Ba;                               \
        *(ushort8*)&sB[buf][ldsw + 32] = Bb;                               \
    }

#define COMPUTE(buf)                                                       \
    {                                                                      \
        short8 af0 = *(const short8*)&sA[buf][ldsAr];                      \
        short8 af1 = *(const short8*)&sA[buf][ldsAr + 32];                 \
        _Pragma("unroll")                                                  \
        for (int t = 0; t < 4; t++) {                                      \
            int bo = (t * 16 + m) * LROW + quad * 8;                       \
            short8 bf0 = *(const short8*)&sB[buf][bo];                     \
            short8 bf1 = *(const short8*)&sB[buf][bo + 32];                \
            acc[t] = __builtin_amdgcn_mfma_f32_16x16x32_bf16(af0, bf0, acc[t], 0, 0, 0); \
            acc[t] = __builtin_amdgcn_mfma_f32_16x16x32_bf16(af1, bf1, acc[t], 0, 0, 0); \
        }                                                                  \
    }

    ushort8 a0a, a0b, b0a, b0b;    // even set
    ushort8 a1a, a1b, b1a, b1b;    // odd set

    LOADSET(a0a, a0b, b0a, b0b, 0)
    LOADSET(a1a, a1b, b1a, b1b, 1)
    WRITESET(0, a0a, a0b, b0a, b0b)
    __syncthreads();

    for (int i = 0; i < 24; i += 2) {
        if (i + 2 < 24) LOADSET(a0a, a0b, b0a, b0b, i + 2)
        COMPUTE(0)
        WRITESET(1, a1a, a1b, b1a, b1b)
        __syncthreads();
        if (i + 3 < 24) LOADSET(a1a, a1b, b1a, b1b, i + 3)
        COMPUTE(1)
        if (i + 2 < 24) WRITESET(0, a0a, a0b, b0a, b0b)
        __syncthreads();
    }

    // epilogue: h2b bf16; D layout: col = lane&15, row = quad*4+reg
#pragma unroll
    for (int t = 0; t < 4; t++)
#pragma unroll
        for (int reg = 0; reg < 4; reg++) {
            int r = row0 + w * 16 + quad * 4 + reg;
            h2b[(size_t)r * 512 + head * 64 + t * 16 + m] = f2bf(acc[t][reg]);
        }

    float as[4], ad[4];
    if (flags[0]) {
        const float* af32 = (const float*)a_raw + head * 128;
#pragma unroll
        for (int t = 0; t < 4; t++) {
            as[t] = af32[t * 16 + m];
            ad[t] = af32[64 + t * 16 + m];
        }
    } else {
        const unsigned short* ab = (const unsigned short*)a_raw + head * 128;
#pragma unroll
        for (int t = 0; t < 4; t++) {
            as[t] = bf2f(ab[t * 16 + m]);
            ad[t] = bf2f(ab[64 + t * 16 + m]);
        }
    }
    float gmax = -1e30f;
#pragma unroll
    for (int reg = 0; reg < 4; reg++) {
        float s1 = as[0] * acc[0][reg] + as[1] * acc[1][reg] + as[2] * acc[2][reg] + as[3] * acc[3][reg];
        float s2 = ad[0] * acc[0][reg] + ad[1] * acc[1][reg] + ad[2] * acc[2][reg] + ad[3] * acc[3][reg];
#pragma unroll
        for (int d = 1; d < 16; d <<= 1) {
            s1 += __shfl_xor(s1, d);
            s2 += __shfl_xor(s2, d);
        }
        gmax = fmaxf(gmax, s2);        // all lanes hold full sum post-butterfly
        if (m == 0) {
            int r = row0 + w * 16 + quad * 4 + reg;
            s_src2[(size_t)r * 8 + head] = s1;
            s_dst2[(size_t)r * 8 + head] = s2;
        }
    }
    // global per-head max of s_dst for attn's softmax bound (1 atomic/wave)
#pragma unroll
    for (int d = 16; d < 64; d <<= 1) gmax = fmaxf(gmax, __shfl_xor(gmax, d));
    if (lane == 0) atomicMax((unsigned int*)&flags[8 + head], encf(gmax));
}

// ---------------------------------------------------------------------------
// Kernel 4: attention + aggregation + row softmax. Block per node i.
// Softmax bound = global per-head max(s_dst) (no per-row max pass).
// Acc loop: explicit 8-deep load batching to break the dependent-load chain.
// ---------------------------------------------------------------------------
__global__ __launch_bounds__(256) void attn_out(const unsigned short* __restrict__ h2b,
                                                const float* __restrict__ s_src2,
                                                const float* __restrict__ s_dst2,
                                                const unsigned long long* __restrict__ adj,
                                                void* __restrict__ out_raw,
                                                const int* __restrict__ flags) {
    __shared__ unsigned short nbrs[4096];
    __shared__ float w_lds[256 * 8];
    __shared__ float sss[8], smax[8], sden[8];
    __shared__ float sredw[4][8];
    __shared__ float sr[8];
    __shared__ int s_cnt;

    int i = blockIdx.x;
    int tid = threadIdx.x;
    int lane = tid & 63, wid = tid >> 6;

    if (tid < 64) {
        unsigned long long word = adj[(size_t)i * 64 + tid];
        int cnt = __popcll(word);
        int incl = cnt;
#pragma unroll
        for (int d = 1; d < 64; d <<= 1) {
            int v = __shfl_up(incl, d);
            if (tid >= d) incl += v;
        }
        int off = incl - cnt;
        unsigned long long w = word;
        int base = tid * 64;
        while (w) {
            int b = __ffsll((unsigned long long)w) - 1;
            nbrs[off++] = (unsigned short)(base + b);
            w &= w - 1;
        }
        if (tid == 63) s_cnt = incl;
    }
    if (tid >= 64 && tid < 72) {
        int h = tid - 64;
        float ss = s_src2[(size_t)i * 8 + h];
        sss[h] = ss;
        float pre = ss + decf((unsigned int)flags[8 + h]);
        smax[h] = pre > 0.f ? pre : ALPHA * pre;
    }
    __syncthreads();
    int cnt = s_cnt;

    int hw = tid & 7;
    int hh = tid >> 5;
    float ssrc_w = sss[hw], maxe_w = smax[hw];
    float den = 0.f, ax = 0.f, ay = 0.f;
    for (int c0 = 0; c0 < cnt; c0 += 256) {
        int csz = min(256, cnt - c0);
        __syncthreads();
        for (int t = tid; t < csz * 8; t += 256) {
            int j = nbrs[c0 + (t >> 3)];
            float e = ssrc_w + s_dst2[(size_t)j * 8 + hw];
            e = e > 0.f ? e : ALPHA * e;
            float w = __expf(e - maxe_w);
            w_lds[t] = w;
            den += w;
        }
        __syncthreads();

        int jj = 0;
        for (; jj + 8 <= csz; jj += 8) {
            int j[8]; unsigned int u[8]; float wv[8];
#pragma unroll
            for (int k = 0; k < 8; k++) j[k] = nbrs[c0 + jj + k];
#pragma unroll
            for (int k = 0; k < 8; k++) u[k] = *(const unsigned int*)(h2b + (size_t)j[k] * 512 + tid * 2);
#pragma unroll
            for (int k = 0; k < 8; k++) wv[k] = w_lds[(jj + k) * 8 + hh];
#pragma unroll
            for (int k = 0; k < 8; k++) {
                ax += wv[k] * bf2f((unsigned short)(u[k] & 0xffffu));
                ay += wv[k] * bf2f((unsigned short)(u[k] >> 16));
            }
        }
        for (; jj < csz; jj++) {
            int j = nbrs[c0 + jj];
            unsigned int u = *(const unsigned int*)(h2b + (size_t)j * 512 + tid * 2);
            float w = w_lds[jj * 8 + hh];
            ax += w * bf2f((unsigned short)(u & 0xffffu));
            ay += w * bf2f((unsigned short)(u >> 16));
        }
    }

    den += __shfl_down(den, 32);
    den += __shfl_down(den, 16);
    den += __shfl_down(den, 8);
    if (lane < 8) sredw[wid][lane] = den;
    __syncthreads();
    if (tid < 8) sden[tid] = sredw[0][tid] + sredw[1][tid] + sredw[2][tid] + sredw[3][tid];
    __syncthreads();
    float dtot = sden[hh];
    float o0 = ax / dtot, o1 = ay / dtot;

    float m2 = fmaxf(o0, o1);
#pragma unroll
    for (int d = 32; d; d >>= 1) m2 = fmaxf(m2, __shfl_down(m2, d));
    if (lane == 0) sr[wid] = m2;
    __syncthreads();
    float m = fmaxf(fmaxf(sr[0], sr[1]), fmaxf(sr[2], sr[3]));
    float e0 = __expf(o0 - m), e1 = __expf(o1 - m);
    float s = e0 + e1;
#pragma unroll
    for (int d = 32; d; d >>= 1) s += __shfl_down(s, d);
    __syncthreads();
    if (lane == 0) sr[wid + 4] = s;
    __syncthreads();
    s = sr[4] + sr[5] + sr[6] + sr[7];

    if (flags[0]) {
        float2* out = (float2*)out_raw;
        out[(size_t)i * 256 + tid] = make_float2(e0 / s, e1 / s);
    } else {
        unsigned int* out = (unsigned int*)out_raw;
        out[(size_t)i * 256 + tid] = (unsigned int)f2bf(e0 / s) | ((unsigned int)f2bf(e1 / s) << 16);
    }
}

// ---------------------------------------------------------------------------
extern "C" void kernel_launch(void* const* d_in, const int* in_sizes, int n_in,
                              void* d_out, int out_size, void* d_ws, size_t ws_size,
                              hipStream_t stream) {
    const int N = 4096, H = 8;
    const int E = in_sizes[1] / 2;

    const void* x = d_in[0];
    const int*  ei = (const int*)d_in[1];
    const void* W = d_in[2];
    const void* a = d_in[3];

    char* ws = (char*)d_ws;
    unsigned short* h2b = (unsigned short*)ws;                           // 4 MB
    float* s_src2 = (float*)(ws + (size_t)4 * 1024 * 1024);              // 128 KB
    float* s_dst2 = s_src2 + (size_t)N * H;                              // 128 KB
    unsigned long long* adj = (unsigned long long*)(ws + (size_t)5 * 1024 * 1024); // 2 MB
    int* flags = (int*)(ws + (size_t)7 * 1024 * 1024 + 512 * 1024);      // flags[0..7], gmax enc [8..15]
    unsigned short* x_hi  = (unsigned short*)(ws + (size_t)8 * 1024 * 1024);       // 4 MB
    unsigned short* x_lo  = (unsigned short*)(ws + (size_t)12 * 1024 * 1024);      // 4 MB
    unsigned short* wt_hi = (unsigned short*)(ws + (size_t)16 * 1024 * 1024);      // 512 KB
    unsigned short* wt_lo = (unsigned short*)(ws + (size_t)16 * 1024 * 1024 + 512 * 1024);

    hipMemsetAsync(adj, 0, (size_t)N * (N / 8), stream);

    split_bf16<<<1152, 256, 0, stream>>>(x, W, x_hi, x_lo, wt_hi, wt_lo, flags);
    build_adj<<<(E + N + 255) / 256, 256, 0, stream>>>(ei, E, N, adj);
    gemm_mfma<<<dim3(N / 64, H), 256, 0, stream>>>(x_hi, x_lo, wt_hi, wt_lo, a,
                                                   h2b, s_src2, s_dst2, flags);
    attn_out<<<N, 256, 0, stream>>>(h2b, s_src2, s_dst2, adj, d_out, flags);
}